// Round 7
// baseline (232.022 us; speedup 1.0000x reference)
//
#include <hip/hip_runtime.h>
#include <hip/hip_cooperative_groups.h>
#include <math.h>

namespace cg = cooperative_groups;

#define BB 8
#define TT 1200
#define NFFT 1024
#define BINS 513
#define LTOT 307200
#define KREV 8192
#define NFRM 34
#define NSAMP 8960
#define OUTOFF 299008          // LTOT - KREV
#define SQRT_SR 154.91933384829668f

// workspace layout (floats)
#define OFF_FR 0               // 8*34*1024 istft frames (windowed)
#define OFF_C  278528          // 8*8960 cumsum
#define OFF_F  350208          // 8*8960 f0 upsampled

__device__ __forceinline__ int rev10(int n) { return (int)(__brev((unsigned)n) >> 22); }

// DIT radix-2, 1024 pts, 512 threads: input at position p = x[br(p)], output natural.
__device__ __forceinline__ void dit1024(float* re, float* im,
                                        const float* twr, const float* twi,
                                        float dir, int tid) {
#pragma unroll
    for (int s = 1; s <= 10; ++s) {
        const int half = 1 << (s - 1);
        __syncthreads();
        int t = tid & (half - 1);
        int i0 = ((tid >> (s - 1)) << s) | t;
        int i1 = i0 + half;
        float wr = twr[half - 1 + t];
        float wi = dir * twi[half - 1 + t];
        float br = re[i1], bi = im[i1];
        float vr = fmaf(br, wr, -(bi * wi));
        float vi = fmaf(br, wi, bi * wr);
        float ar = re[i0], ai = im[i0];
        re[i0] = ar + vr; im[i0] = ai + vi;
        re[i1] = ar - vr; im[i1] = ai - vi;
    }
    __syncthreads();
}

// DIF radix-2, 1024 pts, 512 threads: input natural, output at position p = X[br(p)].
__device__ __forceinline__ void dif1024(float* re, float* im,
                                        const float* twr, const float* twi,
                                        float dir, int tid) {
#pragma unroll
    for (int s = 10; s >= 1; --s) {
        const int half = 1 << (s - 1);
        __syncthreads();
        int t = tid & (half - 1);
        int i0 = ((tid >> (s - 1)) << s) | t;
        int i1 = i0 + half;
        float wr = twr[half - 1 + t];
        float wi = dir * twi[half - 1 + t];
        float ar = re[i0], ai = im[i0];
        float br = re[i1], bi = im[i1];
        re[i0] = ar + br; im[i0] = ai + bi;
        float dr = ar - br, di = ai - bi;
        re[i1] = fmaf(dr, wr, -(di * wi));
        im[i1] = fmaf(dr, wi, di * wr);
    }
    __syncthreads();
}

// tree-scan level offsets within L
#define LV1 0
#define LV2 4480
#define LV3 6720
#define LV4 7840
#define LV5 8400
#define LV6 8680
#define LV7 8820
#define LV8 8890
#define LV9 8925
#define LV10 8942
#define LV11 8950
#define LV12 8954
#define LV13 8956

__global__ __launch_bounds__(512) void fused(const float* __restrict__ f0,
                                             const float* __restrict__ env_per,
                                             const float* __restrict__ env_noi,
                                             const float* __restrict__ rev,
                                             const float* __restrict__ noi,
                                             const float* __restrict__ win,
                                             float* __restrict__ W,
                                             float* __restrict__ out) {
    cg::grid_group grid = cg::this_grid();
    const int bid = blockIdx.x;           // 0..255
    const int tid = threadIdx.x;

    __shared__ __align__(16) float SMEM[17917];   // union: {F,L} | FFT arrays | conv S
    __shared__ float cw[1281], fw[1281];
    __shared__ float twr[1023], twi[1023];

    // ================= phase 0 =================
    for (int x = tid; x < 1023; x += 512) {
        int hb = 31 - __clz(x + 1);
        int half = 1 << hb;
        int t = (x + 1) - half;
        float a = 3.14159265358979323846f * ((float)t / (float)half);
        float sv, cv; sincosf(a, &sv, &cv);
        twr[x] = cv; twi[x] = sv;
    }
    if (bid < 8) {
        // bit-exact f0 upsample + jax.lax.associative_scan tree cumsum (bit-critical)
        const int b = bid;
        float* F = SMEM;            // 8960
        float* L = SMEM + 8960;     // 8957
        for (int i = tid; i < NSAMP; i += 512) {
            float src = __fsub_rn(__fdiv_rn(__fadd_rn((float)i, 0.5f), 256.0f), 0.5f);
            src = fminf(fmaxf(src, 0.0f), (float)(TT - 1));
            int i0 = (int)floorf(src);
            int i1 = i0 + 1; if (i1 > TT - 1) i1 = TT - 1;
            float w = __fsub_rn(src, (float)i0);
            float a0 = __fmul_rn(f0[b * TT + i0], __fsub_rn(1.0f, w));
            float a1 = __fmul_rn(f0[b * TT + i1], w);
            F[i] = __fadd_rn(a0, a1);
        }
        __syncthreads();
        for (int j = tid; j < 4480; j += 512) L[LV1 + j] = __fadd_rn(F[2*j], F[2*j+1]);
        __syncthreads();
        for (int j = tid; j < 2240; j += 512) L[LV2 + j] = __fadd_rn(L[LV1 + 2*j], L[LV1 + 2*j+1]);
        __syncthreads();
        for (int j = tid; j < 1120; j += 512) L[LV3 + j] = __fadd_rn(L[LV2 + 2*j], L[LV2 + 2*j+1]);
        __syncthreads();
        for (int j = tid; j < 560; j += 512)  L[LV4 + j] = __fadd_rn(L[LV3 + 2*j], L[LV3 + 2*j+1]);
        __syncthreads();
        for (int j = tid; j < 280; j += 512)  L[LV5 + j] = __fadd_rn(L[LV4 + 2*j], L[LV4 + 2*j+1]);
        __syncthreads();
        if (tid < 140) L[LV6 + tid] = __fadd_rn(L[LV5 + 2*tid], L[LV5 + 2*tid+1]);
        __syncthreads();
        if (tid < 70)  L[LV7 + tid] = __fadd_rn(L[LV6 + 2*tid], L[LV6 + 2*tid+1]);
        __syncthreads();
        if (tid < 35)  L[LV8 + tid] = __fadd_rn(L[LV7 + 2*tid], L[LV7 + 2*tid+1]);
        __syncthreads();
        if (tid < 17)  L[LV9 + tid] = __fadd_rn(L[LV8 + 2*tid], L[LV8 + 2*tid+1]);
        __syncthreads();
        if (tid < 8)   L[LV10 + tid] = __fadd_rn(L[LV9 + 2*tid], L[LV9 + 2*tid+1]);
        __syncthreads();
        if (tid < 4)   L[LV11 + tid] = __fadd_rn(L[LV10 + 2*tid], L[LV10 + 2*tid+1]);
        __syncthreads();
        if (tid < 2)   L[LV12 + tid] = __fadd_rn(L[LV11 + 2*tid], L[LV11 + 2*tid+1]);
        __syncthreads();
        if (tid < 1)   L[LV13 + tid] = __fadd_rn(L[LV12 + 0], L[LV12 + 1]);
        __syncthreads();
        const int offs[14] = {0, LV1, LV2, LV3, LV4, LV5, LV6, LV7, LV8, LV9, LV10, LV11, LV12, LV13};
        float* Wc = W + OFF_C + b * NSAMP;
        float* Wf = W + OFF_F + b * NSAMP;
        for (int p = tid; p < NSAMP; p += 512) {
            int n = p + 1;
            float acc = 0.f; int pos = 0; bool first = true;
#pragma unroll
            for (int k = 13; k >= 1; --k) {
                if ((n >> k) & 1) {
                    float t = L[offs[k] + (pos >> k)];
                    acc = first ? t : __fadd_rn(acc, t);
                    first = false;
                    pos += (1 << k);
                }
            }
            if (n & 1) {
                float t = F[pos];
                acc = first ? t : __fadd_rn(acc, t);
            }
            Wc[p] = acc;
            Wf[p] = F[p];
        }
    } else {
        // zero-fill output
        float4* out4 = (float4*)out;
        int g = (bid - 8) * 512 + tid;
        for (int idx = g; idx < (BB * LTOT) / 4; idx += 248 * 512)
            out4[idx] = make_float4(0.f, 0.f, 0.f, 0.f);
    }
    grid.sync();

    // ================= phase 1: frame pairs =================
    if (bid < 136) {
        const int b = bid / 17;
        const int fp = (bid - b * 17) * 2;
        const int fg = fp + 1;
        const int cbase = (fp >= 3) ? (256 * fp - 513) : 0;
        for (int w = tid; w < 1281; w += 512) {
            cw[w] = W[OFF_C + b * NSAMP + cbase + w];
            fw[w] = W[OFF_F + b * NSAMP + cbase + w];
        }

        float* wr_  = SMEM;          // 1024
        float* wi_  = SMEM + 1024;
        float* zfr  = SMEM + 2048;
        float* zfi  = SMEM + 3072;
        float* zgr  = SMEM + 4096;
        float* zgi  = SMEM + 5120;
        float* mpfr = SMEM + 6144;   // 513 each
        float* mpfi = SMEM + 6660;
        float* mpgr = SMEM + 7176;
        float* mpgi = SMEM + 7692;

        // log-amp for both frames (temporarily in mpfr/mpgr)
        for (int k = tid; k < BINS; k += 512) {
            float epf = 0.0f;
            if (fp > 0) {
                float f0v = f0[b * TT + (fp - 1)];
                epf = (f0v > 20.0f) ? env_per[(size_t)(b * BINS + k) * TT + (fp - 1)] : 0.0f;
            }
            float f0g = f0[b * TT + (fg - 1)];
            float epg = (f0g > 20.0f) ? env_per[(size_t)(b * BINS + k) * TT + (fg - 1)] : 0.0f;
            mpfr[k] = logf(fmaxf(epf, 1e-5f));
            mpgr[k] = logf(fmaxf(epg, 1e-5f));
        }
        __syncthreads();
        // FFT1: even-real extension, packed
#pragma unroll
        for (int r = 0; r < 2; ++r) {
            int n = tid + 512 * r;
            int kv = (n <= 512) ? n : 1024 - n;
            wr_[n] = mpfr[kv];
            wi_[n] = mpgr[kv];
        }
        dif1024(wr_, wi_, twr, twi, -1.f, tid);
        const float inv = 1.0f / 1024.0f;
#pragma unroll
        for (int r = 0; r < 2; ++r) {
            int p = tid + 512 * r;
            int n = rev10(p);
            float wgt = (n == 0 || n == 512) ? inv : ((n < 512) ? 2.0f * inv : 0.0f);
            wr_[p] *= wgt;
            wi_[p] *= wgt;
        }
        dit1024(wr_, wi_, twr, twi, -1.f, tid);     // Y natural
        for (int k = tid; k < BINS; k += 512) {
            int mk = (1024 - k) & 1023;
            float yr = wr_[k], yi = wi_[k];
            float ymr = wr_[mk], ymi = -wi_[mk];
            float Lfr = 0.5f * (yr + ymr), Lfi = 0.5f * (yi + ymi);
            float dr = yr - ymr, di = yi - ymi;
            float Lgr = 0.5f * di, Lgi = -0.5f * dr;
            float ef = expf(Lfr);
            mpfr[k] = ef * cosf(Lfi); mpfi[k] = ef * sinf(Lfi);
            float eg = expf(Lgr);
            mpgr[k] = eg * cosf(Lgi); mpgi[k] = eg * sinf(Lgi);
        }
        __syncthreads();
        // Z FFTs (noi + i*imp)
#pragma unroll
        for (int r = 0; r < 2; ++r) {
            int n = tid + 512 * r;
            int i = 256 * fp + n - 512; if (i < 0) i = -i;
            float v = 0.0f;
            if (i > 0) {
                int iw = i - cbase;
                float ph  = __fdiv_rn(cw[iw], 24000.0f);
                float sw  = __fsub_rn(ph, floorf(ph));
                float ph2 = __fdiv_rn(cw[iw - 1], 24000.0f);
                float sw2 = __fsub_rn(ph2, floorf(ph2));
                if (__fsub_rn(sw, sw2) < 0.0f)
                    v = __fmul_rn(__fdiv_rn(1.0f, __fsqrt_rn(fmaxf(fw[iw], 20.0f))), SQRT_SR);
            }
            float wv = win[n];
            zfr[n] = __fmul_rn(noi[b * LTOT + i], wv);
            zfi[n] = __fmul_rn(v, wv);
            int i2 = 256 * fg + n - 512; if (i2 < 0) i2 = -i2;
            float v2 = 0.0f;
            if (i2 > 0) {
                int iw = i2 - cbase;
                float ph  = __fdiv_rn(cw[iw], 24000.0f);
                float sw  = __fsub_rn(ph, floorf(ph));
                float ph2 = __fdiv_rn(cw[iw - 1], 24000.0f);
                float sw2 = __fsub_rn(ph2, floorf(ph2));
                if (__fsub_rn(sw, sw2) < 0.0f)
                    v2 = __fmul_rn(__fdiv_rn(1.0f, __fsqrt_rn(fmaxf(fw[iw], 20.0f))), SQRT_SR);
            }
            zgr[n] = __fmul_rn(noi[b * LTOT + i2], wv);
            zgi[n] = __fmul_rn(v2, wv);
        }
        dif1024(zfr, zfi, twr, twi, -1.f, tid);
        dif1024(zgr, zgi, twr, twi, -1.f, tid);
        // build packed spectrum V_f + i*V_g at br positions
#pragma unroll
        for (int r = 0; r < 2; ++r) {
            int p = tid + 512 * r;
            int k = rev10(p);
            int kk = (k <= 512) ? k : 1024 - k;
            bool cj = (k > 512);
            int p1 = rev10(kk);
            int p2 = rev10((1024 - kk) & 1023);
            float vr, vi;
            {
                float z1r = zfr[p1], z1i = zfi[p1];
                float z2r = zfr[p2], z2i = -zfi[p2];
                float Nr = 0.5f * (z1r + z2r), Ni = 0.5f * (z1i + z2i);
                float dr = z1r - z2r, di = z1i - z2i;
                float Ir = 0.5f * di, Ii = -0.5f * dr;
                float mpr = mpfr[kk], mpi2 = mpfi[kk];
                float en = (fp == 0) ? 0.f : env_noi[(size_t)(b * BINS + kk) * TT + (fp - 1)];
                vr = Ir * mpr - Ii * mpi2 + Nr * en;
                vi = Ir * mpi2 + Ii * mpr + Ni * en;
                if (cj) vi = -vi;
            }
            float vgr, vgi;
            {
                float z1r = zgr[p1], z1i = zgi[p1];
                float z2r = zgr[p2], z2i = -zgi[p2];
                float Nr = 0.5f * (z1r + z2r), Ni = 0.5f * (z1i + z2i);
                float dr = z1r - z2r, di = z1i - z2i;
                float Ir = 0.5f * di, Ii = -0.5f * dr;
                float mpr = mpgr[kk], mpi2 = mpgi[kk];
                float en = env_noi[(size_t)(b * BINS + kk) * TT + (fg - 1)];
                vgr = Ir * mpr - Ii * mpi2 + Nr * en;
                vgi = Ir * mpi2 + Ii * mpr + Ni * en;
                if (cj) vgi = -vgi;
            }
            wr_[p] = vr - vgi;
            wi_[p] = vi + vgr;
        }
        dit1024(wr_, wi_, twr, twi, +1.f, tid);
#pragma unroll
        for (int r = 0; r < 2; ++r) {
            int n = tid + 512 * r;
            float wv = win[n];
            W[OFF_FR + (((size_t)(b * NFRM + fp)) << 10) + n] = __fmul_rn(__fmul_rn(wr_[n], inv), wv);
            W[OFF_FR + (((size_t)(b * NFRM + fg)) << 10) + n] = __fmul_rn(__fmul_rn(wi_[n], inv), wv);
        }
    }
    grid.sync();

    // ================= phase 2: triangular conv (320 jobs) =================
    float* S = SMEM;                 // 2560 window
    for (int job = bid; job < 320; job += 256) {
        const int b = job / 40;
        int r = job - b * 40;
        int jt, mt;
        if (r < 4)       { jt = 0; mt = r; }
        else if (r < 12) { jt = 1; mt = r - 4; }
        else if (r < 24) { jt = 2; mt = r - 12; }
        else             { jt = 3; mt = r - 24; }
        const int j0 = jt << 11, m0 = mt << 9;
        const int base = j0 - m0 - 512;
        __syncthreads();
        for (int x = tid; x < 2560; x += 512) {
            int j = base + x;
            float v = 0.f;
            if (j >= 0 && j < KREV) {
                int s = j + 512;
                int flo = (s >= 1023) ? ((s - 1023 + 255) >> 8) : 0;
                int fhi = s >> 8; if (fhi > NFRM - 1) fhi = NFRM - 1;
                float acc = 0.f, wsq = 0.f;
                for (int f = flo; f <= fhi; ++f) {
                    int o = s - (f << 8);
                    acc = __fadd_rn(acc, W[OFF_FR + (((size_t)(b * NFRM + f)) << 10) + o]);
                    float wv = win[o];
                    wsq = __fadd_rn(wsq, __fmul_rn(wv, wv));
                }
                float den = (wsq > 1e-11f) ? wsq : 1.0f;
                v = __fdiv_rn(acc, den);
            }
            S[x] = v;
        }
        __syncthreads();
        const float4* S4 = (const float4*)S;
        const float* Rb = rev + (size_t)b * KREV + m0;
        float y0 = 0.f, y1 = 0.f, y2 = 0.f, y3 = 0.f;
        const int qi = tid + 128;
        float4 Bv = S4[qi];
#pragma unroll 4
        for (int mq = 0; mq < 128; ++mq) {
            float4 A = S4[qi - 1 - mq];
            float4 r4 = *(const float4*)(Rb + 4 * mq);
            y0 = fmaf(r4.x, Bv.x, y0); y0 = fmaf(r4.y, A.w,  y0); y0 = fmaf(r4.z, A.z,  y0); y0 = fmaf(r4.w, A.y,  y0);
            y1 = fmaf(r4.x, Bv.y, y1); y1 = fmaf(r4.y, Bv.x, y1); y1 = fmaf(r4.z, A.w,  y1); y1 = fmaf(r4.w, A.z,  y1);
            y2 = fmaf(r4.x, Bv.z, y2); y2 = fmaf(r4.y, Bv.y, y2); y2 = fmaf(r4.z, Bv.x, y2); y2 = fmaf(r4.w, A.w,  y2);
            y3 = fmaf(r4.x, Bv.w, y3); y3 = fmaf(r4.y, Bv.z, y3); y3 = fmaf(r4.z, Bv.y, y3); y3 = fmaf(r4.w, Bv.x, y3);
            Bv = A;
        }
        float* o = out + (size_t)b * LTOT + OUTOFF + j0 + 4 * tid;
        atomicAdd(o + 0, y0);
        atomicAdd(o + 1, y1);
        atomicAdd(o + 2, y2);
        atomicAdd(o + 3, y3);
    }
}

extern "C" void kernel_launch(void* const* d_in, const int* in_sizes, int n_in,
                              void* d_out, int out_size, void* d_ws, size_t ws_size,
                              hipStream_t stream) {
    const float* f0      = (const float*)d_in[0];
    const float* env_per = (const float*)d_in[1];
    const float* env_noi = (const float*)d_in[2];
    const float* rev     = (const float*)d_in[3];
    const float* noi     = (const float*)d_in[4];
    const float* win     = (const float*)d_in[5];
    float* out = (float*)d_out;
    float* W   = (float*)d_ws;

    void* args[] = {(void*)&f0, (void*)&env_per, (void*)&env_noi, (void*)&rev,
                    (void*)&noi, (void*)&win, (void*)&W, (void*)&out};
    hipLaunchCooperativeKernel((void*)fused, dim3(256), dim3(512), args, 0, stream);
}

// Round 8
// 141.185 us; speedup vs baseline: 1.6434x; 1.6434x over previous
//
#include <hip/hip_runtime.h>
#include <math.h>

#define BB 8
#define TT 1200
#define NFFT 1024
#define BINS 513
#define LTOT 307200
#define KREV 8192
#define NFRM 34
#define NSAMP 8960
#define OUTOFF 299008          // LTOT - KREV
#define SQRT_SR 154.91933384829668f

// workspace layout (floats)
#define OFF_FR   0             // 8*34*1024 istft frames (windowed)

// base-4 digit reversal of a 10-bit index (bit-reverse, then swap adjacent bits)
__device__ __forceinline__ int rev4_10(int n) {
    int r = (int)(__brev((unsigned)n) >> 22);
    return ((r & 0x155) << 1) | ((r & 0x2AA) >> 1);
}

// radix-4 DIF, 1024 pts: input natural, output at position p = X[rev4(p)].
// 256 butterflies/stage; act-gated (inactive threads only hit barriers).
__device__ __forceinline__ void dif4(float* re, float* im,
                                     const float* twr, const float* twi,
                                     float dir, int u, bool act) {
#pragma unroll
    for (int s = 0; s < 5; ++s) {
        const int q = 256 >> (2 * s);
        const int sh = 8 - 2 * s;
        __syncthreads();
        if (act) {
            int t = u & (q - 1);
            int base = ((u >> sh) << (sh + 2)) | t;
            int i0 = base, i1 = base + q, i2 = base + 2 * q, i3 = base + 3 * q;
            float ar = re[i0], ai = im[i0];
            float br = re[i1], bi = im[i1];
            float cr = re[i2], ci = im[i2];
            float dr = re[i3], di = im[i3];
            float t0r = ar + cr, t0i = ai + ci;
            float t1r = ar - cr, t1i = ai - ci;
            float t2r = br + dr, t2i = bi + di;
            float t3r = br - dr, t3i = bi - di;
            float y0r = t0r + t2r, y0i = t0i + t2i;
            float y2r = t0r - t2r, y2i = t0i - t2i;
            float y1r = t1r - dir * t3i, y1i = t1i + dir * t3r;
            float y3r = t1r + dir * t3i, y3i = t1i - dir * t3r;
            float c1 = twr[2 * q - 1 + t], s1 = twi[2 * q - 1 + t];
            float c2 = twr[q - 1 + t],     s2 = twi[q - 1 + t];
            float w1r = c1, w1i = dir * s1;
            float w2r = c2, w2i = dir * s2;
            float w3r = c1 * c2 - s1 * s2;
            float w3i = dir * (c1 * s2 + s1 * c2);
            re[i0] = y0r;                       im[i0] = y0i;
            re[i1] = y1r * w1r - y1i * w1i;     im[i1] = y1r * w1i + y1i * w1r;
            re[i2] = y2r * w2r - y2i * w2i;     im[i2] = y2r * w2i + y2i * w2r;
            re[i3] = y3r * w3r - y3i * w3i;     im[i3] = y3r * w3i + y3i * w3r;
        }
    }
    __syncthreads();
}

// radix-4 DIT, 1024 pts: input at position p = x[rev4(p)], output natural.
__device__ __forceinline__ void dit4(float* re, float* im,
                                     const float* twr, const float* twi,
                                     float dir, int u, bool act) {
#pragma unroll
    for (int s = 0; s < 5; ++s) {
        const int q = 1 << (2 * s);
        const int sh = 2 * s;
        __syncthreads();
        if (act) {
            int t = u & (q - 1);
            int base = ((u >> sh) << (sh + 2)) | t;
            int i0 = base, i1 = base + q, i2 = base + 2 * q, i3 = base + 3 * q;
            float c1 = twr[2 * q - 1 + t], s1 = twi[2 * q - 1 + t];
            float c2 = twr[q - 1 + t],     s2 = twi[q - 1 + t];
            float w1r = c1, w1i = dir * s1;
            float w2r = c2, w2i = dir * s2;
            float w3r = c1 * c2 - s1 * s2;
            float w3i = dir * (c1 * s2 + s1 * c2);
            float ar = re[i0], ai = im[i0];
            float xr = re[i1], xi = im[i1];
            float yr = re[i2], yi = im[i2];
            float zr = re[i3], zi = im[i3];
            float br = xr * w1r - xi * w1i, bi = xr * w1i + xi * w1r;
            float cr = yr * w2r - yi * w2i, ci = yr * w2i + yi * w2r;
            float dr = zr * w3r - zi * w3i, di = zr * w3i + zi * w3r;
            float t0r = ar + cr, t0i = ai + ci;
            float t1r = ar - cr, t1i = ai - ci;
            float t2r = br + dr, t2i = bi + di;
            float t3r = br - dr, t3i = bi - di;
            re[i0] = t0r + t2r;            im[i0] = t0i + t2i;
            re[i2] = t0r - t2r;            im[i2] = t0i - t2i;
            re[i1] = t1r - dir * t3i;      im[i1] = t1i + dir * t3r;
            re[i3] = t1r + dir * t3i;      im[i3] = t1i - dir * t3r;
        }
    }
    __syncthreads();
}

// tree-scan level offsets within L
#define LV1 0
#define LV2 4480
#define LV3 6720
#define LV4 7840
#define LV5 8400
#define LV6 8680
#define LV7 8820
#define LV8 8890
#define LV9 8925
#define LV10 8942
#define LV11 8950
#define LV12 8954
#define LV13 8956

// KFRM: one block = one frame pair (f=2t, g=2t+1), 512 threads.
// Phase 0: zero-fill out; twiddles. Phase 1: bit-exact f0 upsample + tree cumsum
// (merged-level schedule; per-node __fadd_rn arithmetic byte-identical).
// Phase 2: 4 radix-4 FFT passes -> windowed istft frames.
__global__ __launch_bounds__(512) void kfrm(const float* __restrict__ f0,
                                            const float* __restrict__ env_per,
                                            const float* __restrict__ env_noi,
                                            const float* __restrict__ noi,
                                            const float* __restrict__ win,
                                            float* __restrict__ W,
                                            float* __restrict__ out) {
    const int bid = blockIdx.x;           // 0..135
    const int tid = threadIdx.x;
    const int b = bid / 17;
    const int fp = (bid - b * 17) * 2;    // f = fp, g = fp+1
    const int fg = fp + 1;

    __shared__ __align__(16) float SMEM[17917];   // union: {F[8960],L[8957]} | FFT arrays
    __shared__ float cw[1281], fw[1281];
    __shared__ float twr[1023], twi[1023];

    // ---- phase 0: zero-fill out (grid-stride), twiddles
    {
        float4* out4 = (float4*)out;
        int g = bid * 512 + tid;
        for (int idx = g; idx < (BB * LTOT) / 4; idx += 136 * 512)
            out4[idx] = make_float4(0.f, 0.f, 0.f, 0.f);
    }
    for (int x = tid; x < 1023; x += 512) {
        int hb = 31 - __clz(x + 1);
        int half = 1 << hb;
        int t = (x + 1) - half;
        float a = 3.14159265358979323846f * ((float)t / (float)half);
        float sv, cv; sincosf(a, &sv, &cv);
        twr[x] = cv; twi[x] = sv;
    }

    // ---- phase 1: bit-exact f0 upsample + tree cumsum (merged levels)
    float* F = SMEM;            // 8960
    float* L = SMEM + 8960;     // 8957
    for (int i = tid; i < NSAMP; i += 512) {
        float src = __fsub_rn(__fdiv_rn(__fadd_rn((float)i, 0.5f), 256.0f), 0.5f);
        src = fminf(fmaxf(src, 0.0f), (float)(TT - 1));
        int i0 = (int)floorf(src);
        int i1 = i0 + 1; if (i1 > TT - 1) i1 = TT - 1;
        float w = __fsub_rn(src, (float)i0);
        float a0 = __fmul_rn(f0[b * TT + i0], __fsub_rn(1.0f, w));
        float a1 = __fmul_rn(f0[b * TT + i1], w);
        F[i] = __fadd_rn(a0, a1);
    }
    __syncthreads();
    for (int j = tid; j < 2240; j += 512) {           // levels 1+2
        float a = __fadd_rn(F[4*j],     F[4*j + 1]);
        float c = __fadd_rn(F[4*j + 2], F[4*j + 3]);
        L[LV1 + 2*j] = a; L[LV1 + 2*j + 1] = c;
        L[LV2 + j] = __fadd_rn(a, c);
    }
    __syncthreads();
    for (int j = tid; j < 560; j += 512) {            // levels 3+4
        float a = __fadd_rn(L[LV2 + 4*j],     L[LV2 + 4*j + 1]);
        float c = __fadd_rn(L[LV2 + 4*j + 2], L[LV2 + 4*j + 3]);
        L[LV3 + 2*j] = a; L[LV3 + 2*j + 1] = c;
        L[LV4 + j] = __fadd_rn(a, c);
    }
    __syncthreads();
    if (tid < 140) {                                  // levels 5+6
        int j = tid;
        float a = __fadd_rn(L[LV4 + 4*j],     L[LV4 + 4*j + 1]);
        float c = __fadd_rn(L[LV4 + 4*j + 2], L[LV4 + 4*j + 3]);
        L[LV5 + 2*j] = a; L[LV5 + 2*j + 1] = c;
        L[LV6 + j] = __fadd_rn(a, c);
    }
    __syncthreads();
    if (tid < 35) {                                   // levels 7+8
        int j = tid;
        float a = __fadd_rn(L[LV6 + 4*j],     L[LV6 + 4*j + 1]);
        float c = __fadd_rn(L[LV6 + 4*j + 2], L[LV6 + 4*j + 3]);
        L[LV7 + 2*j] = a; L[LV7 + 2*j + 1] = c;
        L[LV8 + j] = __fadd_rn(a, c);
    }
    __syncthreads();
    if (tid < 9) {                                    // levels 9+10 (L9 has 17 nodes)
        int j = tid;
        if (j < 8) {
            float a = __fadd_rn(L[LV8 + 4*j],     L[LV8 + 4*j + 1]);
            float c = __fadd_rn(L[LV8 + 4*j + 2], L[LV8 + 4*j + 3]);
            L[LV9 + 2*j] = a; L[LV9 + 2*j + 1] = c;
            L[LV10 + j] = __fadd_rn(a, c);
        } else {
            L[LV9 + 16] = __fadd_rn(L[LV8 + 32], L[LV8 + 33]);
        }
    }
    __syncthreads();
    if (tid == 0) {                                   // levels 11..13
        float a0 = __fadd_rn(L[LV10 + 0], L[LV10 + 1]);
        float a1 = __fadd_rn(L[LV10 + 2], L[LV10 + 3]);
        float a2 = __fadd_rn(L[LV10 + 4], L[LV10 + 5]);
        float a3 = __fadd_rn(L[LV10 + 6], L[LV10 + 7]);
        L[LV11 + 0] = a0; L[LV11 + 1] = a1; L[LV11 + 2] = a2; L[LV11 + 3] = a3;
        float b0 = __fadd_rn(a0, a1), b1 = __fadd_rn(a2, a3);
        L[LV12 + 0] = b0; L[LV12 + 1] = b1;
        L[LV13 + 0] = __fadd_rn(b0, b1);
    }
    __syncthreads();
    const int cbase = (fp >= 3) ? (256 * fp - 513) : 0;
    {
        const int offs[14] = {0, LV1, LV2, LV3, LV4, LV5, LV6, LV7, LV8, LV9, LV10, LV11, LV12, LV13};
        for (int w = tid; w < 1281; w += 512) {
            int p = cbase + w;
            if (p < NSAMP) {
                int n = p + 1;
                float acc = 0.f; int pos = 0; bool first = true;
#pragma unroll
                for (int k = 13; k >= 1; --k) {
                    if ((n >> k) & 1) {
                        float t = L[offs[k] + (pos >> k)];
                        acc = first ? t : __fadd_rn(acc, t);
                        first = false;
                        pos += (1 << k);
                    }
                }
                if (n & 1) {
                    float t = F[pos];
                    acc = first ? t : __fadd_rn(acc, t);
                }
                cw[w] = acc;
                fw[w] = F[p];
            }
        }
    }
    __syncthreads();

    // ---- phase 2: FFT pipeline (union reused)
    float* wr_  = SMEM;          // 1024
    float* wi_  = SMEM + 1024;
    float* zfr  = SMEM + 2048;
    float* zfi  = SMEM + 3072;
    float* zgr  = SMEM + 4096;
    float* zgi  = SMEM + 5120;
    float* mpfr = SMEM + 6144;   // 513 each
    float* mpfi = SMEM + 6660;
    float* mpgr = SMEM + 7176;
    float* mpgi = SMEM + 7692;
    const int u = tid & 255;
    const bool lo = (tid < 256);

    // log-amp for both frames (temporarily in mpfr/mpgr)
    for (int k = tid; k < BINS; k += 512) {
        float epf = 0.0f;
        if (fp > 0) {
            float f0v = f0[b * TT + (fp - 1)];
            epf = (f0v > 20.0f) ? env_per[(size_t)(b * BINS + k) * TT + (fp - 1)] : 0.0f;
        }
        float f0g = f0[b * TT + (fg - 1)];
        float epg = (f0g > 20.0f) ? env_per[(size_t)(b * BINS + k) * TT + (fg - 1)] : 0.0f;
        mpfr[k] = logf(fmaxf(epf, 1e-5f));
        mpgr[k] = logf(fmaxf(epg, 1e-5f));
    }
    __syncthreads();
    // FFT1: even-real extension, packed la_f + i*la_g
#pragma unroll
    for (int r = 0; r < 2; ++r) {
        int n = tid + 512 * r;
        int kv = (n <= 512) ? n : 1024 - n;
        wr_[n] = mpfr[kv];
        wi_[n] = mpgr[kv];
    }
    dif4(wr_, wi_, twr, twi, -1.f, u, lo);
    // lifter (position p holds cepstrum index n = rev4(p)); scale 1/1024
    const float inv = 1.0f / 1024.0f;
#pragma unroll
    for (int r = 0; r < 2; ++r) {
        int p = tid + 512 * r;
        int n = rev4_10(p);
        float wgt = (n == 0 || n == 512) ? inv : ((n < 512) ? 2.0f * inv : 0.0f);
        wr_[p] *= wgt;
        wi_[p] *= wgt;
    }
    dit4(wr_, wi_, twr, twi, -1.f, u, lo);      // Y natural = FFT(l_f) + i FFT(l_g)
    // unpack + exp -> MP
    for (int k = tid; k < BINS; k += 512) {
        int mk = (1024 - k) & 1023;
        float yr = wr_[k], yi = wi_[k];
        float ymr = wr_[mk], ymi = -wi_[mk];
        float Lfr = 0.5f * (yr + ymr), Lfi = 0.5f * (yi + ymi);
        float dr = yr - ymr, di = yi - ymi;
        float Lgr = 0.5f * di, Lgi = -0.5f * dr;
        float ef = expf(Lfr);
        mpfr[k] = ef * cosf(Lfi); mpfi[k] = ef * sinf(Lfi);
        float eg = expf(Lgr);
        mpgr[k] = eg * cosf(Lgi); mpgi[k] = eg * sinf(Lgi);
    }
    __syncthreads();
    // Z fill (noi + i*imp), natural order
#pragma unroll
    for (int r = 0; r < 2; ++r) {
        int n = tid + 512 * r;
        int i = 256 * fp + n - 512; if (i < 0) i = -i;
        float v = 0.0f;
        if (i > 0) {
            int iw = i - cbase;
            float ph  = __fdiv_rn(cw[iw], 24000.0f);
            float sw  = __fsub_rn(ph, floorf(ph));
            float ph2 = __fdiv_rn(cw[iw - 1], 24000.0f);
            float sw2 = __fsub_rn(ph2, floorf(ph2));
            if (__fsub_rn(sw, sw2) < 0.0f)
                v = __fmul_rn(__fdiv_rn(1.0f, __fsqrt_rn(fmaxf(fw[iw], 20.0f))), SQRT_SR);
        }
        float wv = win[n];
        zfr[n] = __fmul_rn(noi[b * LTOT + i], wv);
        zfi[n] = __fmul_rn(v, wv);
        int i2 = 256 * fg + n - 512; if (i2 < 0) i2 = -i2;
        float v2 = 0.0f;
        if (i2 > 0) {
            int iw = i2 - cbase;
            float ph  = __fdiv_rn(cw[iw], 24000.0f);
            float sw  = __fsub_rn(ph, floorf(ph));
            float ph2 = __fdiv_rn(cw[iw - 1], 24000.0f);
            float sw2 = __fsub_rn(ph2, floorf(ph2));
            if (__fsub_rn(sw, sw2) < 0.0f)
                v2 = __fmul_rn(__fdiv_rn(1.0f, __fsqrt_rn(fmaxf(fw[iw], 20.0f))), SQRT_SR);
        }
        zgr[n] = __fmul_rn(noi[b * LTOT + i2], wv);
        zgi[n] = __fmul_rn(v2, wv);
    }
    // concurrent FFTs: threads 0-255 on zf, 256-511 on zg
    dif4(lo ? zfr : zgr, lo ? zfi : zgi, twr, twi, -1.f, u, true);
    // build packed spectrum V_f + i*V_g at rev4 positions
#pragma unroll
    for (int r = 0; r < 2; ++r) {
        int p = tid + 512 * r;
        int k = rev4_10(p);
        int kk = (k <= 512) ? k : 1024 - k;
        bool cj = (k > 512);
        int p1 = rev4_10(kk);
        int p2 = rev4_10((1024 - kk) & 1023);
        float vr, vi;
        {
            float z1r = zfr[p1], z1i = zfi[p1];
            float z2r = zfr[p2], z2i = -zfi[p2];
            float Nr = 0.5f * (z1r + z2r), Ni = 0.5f * (z1i + z2i);
            float dr = z1r - z2r, di = z1i - z2i;
            float Ir = 0.5f * di, Ii = -0.5f * dr;
            float mpr = mpfr[kk], mpi2 = mpfi[kk];
            float en = (fp == 0) ? 0.f : env_noi[(size_t)(b * BINS + kk) * TT + (fp - 1)];
            vr = Ir * mpr - Ii * mpi2 + Nr * en;
            vi = Ir * mpi2 + Ii * mpr + Ni * en;
            if (cj) vi = -vi;
        }
        float vgr, vgi;
        {
            float z1r = zgr[p1], z1i = zgi[p1];
            float z2r = zgr[p2], z2i = -zgi[p2];
            float Nr = 0.5f * (z1r + z2r), Ni = 0.5f * (z1i + z2i);
            float dr = z1r - z2r, di = z1i - z2i;
            float Ir = 0.5f * di, Ii = -0.5f * dr;
            float mpr = mpgr[kk], mpi2 = mpgi[kk];
            float en = env_noi[(size_t)(b * BINS + kk) * TT + (fg - 1)];
            vgr = Ir * mpr - Ii * mpi2 + Nr * en;
            vgi = Ir * mpi2 + Ii * mpr + Ni * en;
            if (cj) vgi = -vgi;
        }
        wr_[p] = vr - vgi;
        wi_[p] = vi + vgr;
    }
    dit4(wr_, wi_, twr, twi, +1.f, u, lo);      // natural: 1024*(x_f + i*x_g)
#pragma unroll
    for (int r = 0; r < 2; ++r) {
        int n = tid + 512 * r;
        float wv = win[n];
        W[OFF_FR + (((size_t)(b * NFRM + fp)) << 10) + n] = __fmul_rn(__fmul_rn(wr_[n], inv), wv);
        W[OFF_FR + (((size_t)(b * NFRM + fg)) << 10) + n] = __fmul_rn(__fmul_rn(wi_[n], inv), wv);
    }
}

// K4: triangular conv with inline overlap-add. 576 blocks x 256 thr:
// 1024-out x 512-tap tiles; S window built by OLA+wsq-normalize on the fly;
// rev read at block-uniform addresses (scalar path); atomicAdd partials.
__global__ __launch_bounds__(256) void k4(const float* __restrict__ rev,
                                          const float* __restrict__ win,
                                          const float* __restrict__ W,
                                          float* __restrict__ out) {
    const int tid = threadIdx.x;
    const int b = blockIdx.x / 72;
    int r = blockIdx.x - b * 72;
    int jt = 0, acc0 = 0;
    while (acc0 + 2 * (jt + 1) <= r) { acc0 += 2 * (jt + 1); ++jt; }
    const int mc = r - acc0;
    const int j0 = jt << 10, m0 = mc << 9;

    __shared__ __align__(16) float S[1536];
    const int base = j0 - m0 - 512;
    for (int x = tid; x < 1536; x += 256) {
        int j = base + x;
        float v = 0.f;
        if (j >= 0 && j < KREV) {
            int s = j + 512;
            int flo = (s >= 1023) ? ((s - 1023 + 255) >> 8) : 0;
            int fhi = s >> 8; if (fhi > NFRM - 1) fhi = NFRM - 1;
            float acc = 0.f, wsq = 0.f;
            for (int f = flo; f <= fhi; ++f) {
                int o = s - (f << 8);
                acc = __fadd_rn(acc, W[OFF_FR + (((size_t)(b * NFRM + f)) << 10) + o]);
                float wv = win[o];
                wsq = __fadd_rn(wsq, __fmul_rn(wv, wv));
            }
            float den = (wsq > 1e-11f) ? wsq : 1.0f;
            v = __fdiv_rn(acc, den);
        }
        S[x] = v;
    }
    __syncthreads();

    const float4* S4 = (const float4*)S;
    const float* Rb = rev + b * KREV + m0;
    float y0 = 0.f, y1 = 0.f, y2 = 0.f, y3 = 0.f;
    const int qi = tid + 128;
    float4 Bv = S4[qi];
#pragma unroll 4
    for (int mq = 0; mq < 128; ++mq) {
        float4 A = S4[qi - 1 - mq];
        float4 r4 = *(const float4*)(Rb + 4 * mq);
        y0 = fmaf(r4.x, Bv.x, y0); y0 = fmaf(r4.y, A.w,  y0); y0 = fmaf(r4.z, A.z,  y0); y0 = fmaf(r4.w, A.y,  y0);
        y1 = fmaf(r4.x, Bv.y, y1); y1 = fmaf(r4.y, Bv.x, y1); y1 = fmaf(r4.z, A.w,  y1); y1 = fmaf(r4.w, A.z,  y1);
        y2 = fmaf(r4.x, Bv.z, y2); y2 = fmaf(r4.y, Bv.y, y2); y2 = fmaf(r4.z, Bv.x, y2); y2 = fmaf(r4.w, A.w,  y2);
        y3 = fmaf(r4.x, Bv.w, y3); y3 = fmaf(r4.y, Bv.z, y3); y3 = fmaf(r4.z, Bv.y, y3); y3 = fmaf(r4.w, Bv.x, y3);
        Bv = A;
    }
    float* o = out + (size_t)b * LTOT + OUTOFF + j0 + 4 * tid;
    atomicAdd(o + 0, y0);
    atomicAdd(o + 1, y1);
    atomicAdd(o + 2, y2);
    atomicAdd(o + 3, y3);
}

extern "C" void kernel_launch(void* const* d_in, const int* in_sizes, int n_in,
                              void* d_out, int out_size, void* d_ws, size_t ws_size,
                              hipStream_t stream) {
    const float* f0      = (const float*)d_in[0];
    const float* env_per = (const float*)d_in[1];
    const float* env_noi = (const float*)d_in[2];
    const float* rev     = (const float*)d_in[3];
    const float* noi     = (const float*)d_in[4];
    const float* win     = (const float*)d_in[5];
    float* out = (float*)d_out;
    float* W   = (float*)d_ws;

    kfrm<<<dim3(136), dim3(512), 0, stream>>>(f0, env_per, env_noi, noi, win, W, out);
    k4<<<dim3(576),   dim3(256), 0, stream>>>(rev, win, W, out);
}